// Round 2
// baseline (4063.188 us; speedup 1.0000x reference)
//
#include <hip/hip_runtime.h>
#include <cstdint>
#include <cstddef>

#define NN   2048
#define BB   16
#define TT   12
#define FUT  12
#define HH   64
#define CF   198     // 3*(IN+H) = 3*66
#define GG   256     // 4*H
#define ELLW 72      // max nnz per row (deg ~Binom(2047, 8/2048), P(>71) ~ 0)

__device__ __forceinline__ float sigmoidf_(float x) {
    return 1.f / (1.f + __expf(-x));
}
__device__ __forceinline__ float tanhf_(float x) {
    const float e = __expf(2.f * x);
    return 1.f - 2.f / (e + 1.f);
}

// ---------------------------------------------------------------------------
// Build ELL representation of L, deterministically (ascending column order).
// One block per row; thread t owns columns [8t, 8t+8); block-wide prefix sum
// gives each thread its write offset, so entry order == ascending column.
// ---------------------------------------------------------------------------
__global__ __launch_bounds__(256) void build_ell(
    const float* __restrict__ L, int* __restrict__ cols,
    float* __restrict__ vals, int* __restrict__ cnt)
{
    const int n = blockIdx.x;
    const int t = threadIdx.x;
    const float* row = L + (size_t)n * NN;
    float v[8];
    int c = 0;
#pragma unroll
    for (int i = 0; i < 8; ++i) {
        v[i] = row[t * 8 + i];
        c += (v[i] != 0.f);
    }
    __shared__ int s[256];
    s[t] = c;
    __syncthreads();
    for (int d = 1; d < 256; d <<= 1) {
        int add = (t >= d) ? s[t - d] : 0;
        __syncthreads();
        s[t] += add;
        __syncthreads();
    }
    int o = s[t] - c;   // exclusive prefix
#pragma unroll
    for (int i = 0; i < 8; ++i) {
        if (v[i] != 0.f) {
            if (o < ELLW) {
                cols[n * ELLW + o] = t * 8 + i;
                vals[n * ELLW + o] = v[i];
            }
            ++o;
        }
    }
    if (t == 255) cnt[n] = (s[255] < ELLW) ? s[255] : ELLW;
}

// ---------------------------------------------------------------------------
// t1 = L_sparse @ comb, comb = [x(2) | h(64)] per (b,n).
// One wave per row (b,n); lane = feature. Features 64,65 handled by lanes 0,1.
// x[b,m,f] = xin[b*xbstride + m*2 + f]
// ---------------------------------------------------------------------------
__global__ __launch_bounds__(256) void spmm_t1(
    const float* __restrict__ xin, int xbstride,
    const float* __restrict__ h,
    const int* __restrict__ cols, const float* __restrict__ vals,
    const int* __restrict__ cnt, float* __restrict__ t1)
{
    const int wid = threadIdx.x >> 6, lane = threadIdx.x & 63;
    const int r = blockIdx.x * 4 + wid;           // 0 .. B*N-1
    const int b = r >> 11, n = r & (NN - 1);
    const float* xb = xin + (size_t)b * xbstride;
    const float* hb = h + ((size_t)b << 11) * HH;
    const int cn = cnt[n];
    float a0 = 0.f, a1 = 0.f;
    for (int j = 0; j < cn; ++j) {
        const int m = cols[n * ELLW + j];
        const float v = vals[n * ELLW + j];
        const float comb = (lane < 2) ? xb[m * 2 + lane] : hb[(size_t)m * HH + lane - 2];
        a0 += v * comb;
        if (lane < 2) a1 += v * hb[(size_t)m * HH + 62 + lane];
    }
    float* o = t1 + (size_t)r * 66;
    o[lane] = a0;
    if (lane < 2) o[64 + lane] = a1;
}

// ---------------------------------------------------------------------------
// Fused cell step: build cheb tile [comb|t1|t2] in LDS, GEMM vs W (198x256),
// LSTM elementwise, in-place h/c update; optionally x = tanh(h@W0+b0) ->
// xout and out[:, jslot].
// Block: 256 threads, 64 rows. Wave w owns rows [16w,16w+16), lane = hidden
// unit; each thread accumulates 16 rows x {i,f,o,g} of its unit.
// ---------------------------------------------------------------------------
__global__ __launch_bounds__(256) void cell_step(
    const float* __restrict__ xin, int xbstride,
    float* __restrict__ h, float* __restrict__ c,
    const float* __restrict__ t1g,
    const int* __restrict__ cols, const float* __restrict__ vals,
    const int* __restrict__ cnt,
    const float* __restrict__ W, const float* __restrict__ bc,
    const float* __restrict__ W0, const float* __restrict__ b0,
    float* __restrict__ xout, float* __restrict__ out, int jslot)
{
    __shared__ float A[64][200];   // cheb features, padded stride
    const int tid = threadIdx.x, wid = tid >> 6, lane = tid & 63;
    const int row0 = blockIdx.x * 64;

    // ---- build cheb tile: each wave handles rows wid, wid+4, ...
    for (int rr = wid; rr < 64; rr += 4) {
        const int r = row0 + rr, b = r >> 11, n = r & (NN - 1);
        const float* xb = xin + (size_t)b * xbstride;
        const float* hb = h + ((size_t)b << 11) * HH;
        const float comb0 = (lane < 2) ? xb[n * 2 + lane] : hb[(size_t)n * HH + lane - 2];
        float comb1 = 0.f;
        if (lane < 2) comb1 = hb[(size_t)n * HH + 62 + lane];
        A[rr][lane] = comb0;
        if (lane < 2) A[rr][64 + lane] = comb1;
        const float* t1r = t1g + (size_t)r * 66;
        A[rr][66 + lane] = t1r[lane];
        if (lane < 2) A[rr][130 + lane] = t1r[64 + lane];
        float a0 = 0.f, a1 = 0.f;
        const int cn = cnt[n];
        for (int j = 0; j < cn; ++j) {
            const int m = cols[n * ELLW + j];
            const float v = vals[n * ELLW + j];
            const float* tm = t1g + (((size_t)b << 11) + m) * 66;
            a0 += v * tm[lane];
            if (lane < 2) a1 += v * tm[64 + lane];
        }
        A[rr][132 + lane] = 2.f * a0 - comb0;
        if (lane < 2) A[rr][196 + lane] = 2.f * a1 - comb1;
    }
    __syncthreads();

    // ---- GEMM: gates[r][u + 64j] = sum_k A[r][k] * W[k][u + 64j]
    float acc[16][4];
#pragma unroll
    for (int i = 0; i < 16; ++i) {
        acc[i][0] = 0.f; acc[i][1] = 0.f; acc[i][2] = 0.f; acc[i][3] = 0.f;
    }
#pragma unroll 1
    for (int k0 = 0; k0 < 196; k0 += 4) {
        float w[4][4];
#pragma unroll
        for (int kk = 0; kk < 4; ++kk) {
            const float* wr = W + (size_t)(k0 + kk) * GG;
            w[kk][0] = wr[lane];
            w[kk][1] = wr[64 + lane];
            w[kk][2] = wr[128 + lane];
            w[kk][3] = wr[192 + lane];
        }
#pragma unroll
        for (int i = 0; i < 16; ++i) {
            const float4 av = *(const float4*)&A[wid * 16 + i][k0];
            const float aa[4] = {av.x, av.y, av.z, av.w};
#pragma unroll
            for (int kk = 0; kk < 4; ++kk) {
                acc[i][0] += aa[kk] * w[kk][0];
                acc[i][1] += aa[kk] * w[kk][1];
                acc[i][2] += aa[kk] * w[kk][2];
                acc[i][3] += aa[kk] * w[kk][3];
            }
        }
    }
    // remainder k = 196, 197
#pragma unroll
    for (int k = 196; k < 198; ++k) {
        const float* wr = W + (size_t)k * GG;
        const float w0 = wr[lane], w1 = wr[64 + lane], w2 = wr[128 + lane], w3 = wr[192 + lane];
#pragma unroll
        for (int i = 0; i < 16; ++i) {
            const float a = A[wid * 16 + i][k];
            acc[i][0] += a * w0; acc[i][1] += a * w1;
            acc[i][2] += a * w2; acc[i][3] += a * w3;
        }
    }

    // ---- LSTM elementwise + optional projection
    const float bi = bc[lane], bf = bc[64 + lane], bo = bc[128 + lane], bg = bc[192 + lane];
    const float w00 = W0[lane * 2], w01 = W0[lane * 2 + 1];
    const float b00 = b0[0], b01 = b0[1];
#pragma unroll
    for (int i = 0; i < 16; ++i) {
        const int r = row0 + wid * 16 + i;
        const size_t idx = (size_t)r * HH + lane;
        const float cold = c[idx];
        const float ig = sigmoidf_(acc[i][0] + bi);
        const float fg = sigmoidf_(acc[i][1] + bf);
        const float og = sigmoidf_(acc[i][2] + bo);
        const float gg = tanhf_(acc[i][3] + bg);
        const float c2 = fg * cold + ig * gg;
        const float h2 = og * tanhf_(c2);
        c[idx] = c2;
        h[idx] = h2;
        if (jslot >= 0) {
            float s0 = h2 * w00, s1 = h2 * w01;
#pragma unroll
            for (int d = 32; d; d >>= 1) {
                s0 += __shfl_xor(s0, d, 64);
                s1 += __shfl_xor(s1, d, 64);
            }
            if (lane == 0) {
                const float y0 = tanhf_(s0 + b00);
                const float y1 = tanhf_(s1 + b01);
                const int b = r >> 11, n = r & (NN - 1);
                xout[(size_t)r * 2]     = y0;
                xout[(size_t)r * 2 + 1] = y1;
                float* op = out + (((size_t)b * FUT + jslot) * NN + n) * 2;
                op[0] = y0;
                op[1] = y1;
            }
        }
    }
}

// ---------------------------------------------------------------------------
extern "C" void kernel_launch(void* const* d_in, const int* in_sizes, int n_in,
                              void* d_out, int out_size, void* d_ws, size_t ws_size,
                              hipStream_t stream)
{
    const float* input = (const float*)d_in[0];   // [B,T,N,2]
    const float* L     = (const float*)d_in[1];   // [N,N]
    const float* W     = (const float*)d_in[2];   // [198,256]
    const float* bc    = (const float*)d_in[3];   // [256]
    const float* W0    = (const float*)d_in[4];   // [64,2]
    const float* b0    = (const float*)d_in[5];   // [2]
    // d_in[6]: future == 12 (fixed by the problem spec)

    char* ws = (char*)d_ws;
    size_t off = 0;
    auto carve = [&](size_t bytes) {
        void* p = ws + off;
        off += (bytes + 255) & ~(size_t)255;
        return p;
    };
    int*   cols = (int*)  carve((size_t)NN * ELLW * 4);
    float* vals = (float*)carve((size_t)NN * ELLW * 4);
    int*   cnt  = (int*)  carve((size_t)NN * 4);
    float* t1   = (float*)carve((size_t)BB * NN * 66 * 4);
    float* h    = (float*)carve((size_t)BB * NN * HH * 4);
    float* c    = (float*)carve((size_t)BB * NN * HH * 4);
    float* xbuf = (float*)carve((size_t)BB * NN * 2 * 4);
    float* out  = (float*)d_out;

    build_ell<<<NN, 256, 0, stream>>>(L, cols, vals, cnt);
    hipMemsetAsync(h, 0, (size_t)BB * NN * HH * 4, stream);
    hipMemsetAsync(c, 0, (size_t)BB * NN * HH * 4, stream);

    const int gridT1 = (BB * NN) / 4;
    const int gridC  = (BB * NN) / 64;

    // encoder: 12 steps; last step also emits out[:,0] and xbuf
    for (int t = 0; t < TT; ++t) {
        const float* xin = input + (size_t)t * NN * 2;
        const int xstride = TT * NN * 2;
        spmm_t1<<<gridT1, 256, 0, stream>>>(xin, xstride, h, cols, vals, cnt, t1);
        cell_step<<<gridC, 256, 0, stream>>>(xin, xstride, h, c, t1, cols, vals, cnt,
                                             W, bc, W0, b0, xbuf, out,
                                             (t == TT - 1) ? 0 : -1);
    }
    // decoder: 11 steps -> out[:,1..11]
    for (int j = 1; j < FUT; ++j) {
        spmm_t1<<<gridT1, 256, 0, stream>>>(xbuf, NN * 2, h, cols, vals, cnt, t1);
        cell_step<<<gridC, 256, 0, stream>>>(xbuf, NN * 2, h, c, t1, cols, vals, cnt,
                                             W, bc, W0, b0, xbuf, out, j);
    }
}

// Round 3
// 2825.218 us; speedup vs baseline: 1.4382x; 1.4382x over previous
//
#include <hip/hip_runtime.h>
#include <cstdint>
#include <cstddef>

#define NN   2048
#define BB   16
#define TT   12
#define FUT  12
#define HH   64
#define GG   256     // 4*H
#define KP   224     // K=198 padded to 7*32
#define ELLW 72

typedef __attribute__((ext_vector_type(8))) short bf16x8;
typedef __attribute__((ext_vector_type(4))) float f32x4;

__device__ __forceinline__ float sigmoidf_(float x) {
    return 1.f / (1.f + __expf(-x));
}
__device__ __forceinline__ float tanhf_(float x) {
    const float e = __expf(2.f * x);
    return 1.f - 2.f / (e + 1.f);
}
__device__ __forceinline__ unsigned short f2bf(float x) {
    unsigned u = __builtin_bit_cast(unsigned, x);
    u += 0x7fffu + ((u >> 16) & 1u);
    return (unsigned short)(u >> 16);
}
__device__ __forceinline__ float bf2f(unsigned short s) {
    unsigned u = ((unsigned)s) << 16;
    return __builtin_bit_cast(float, u);
}

// ---------------------------------------------------------------------------
// ELL of L, deterministic ascending-column order.
// ---------------------------------------------------------------------------
__global__ __launch_bounds__(256) void build_ell(
    const float* __restrict__ L, int* __restrict__ cols,
    float* __restrict__ vals, int* __restrict__ cnt)
{
    const int n = blockIdx.x;
    const int t = threadIdx.x;
    const float* row = L + (size_t)n * NN;
    float v[8];
    int c = 0;
#pragma unroll
    for (int i = 0; i < 8; ++i) {
        v[i] = row[t * 8 + i];
        c += (v[i] != 0.f);
    }
    __shared__ int s[256];
    s[t] = c;
    __syncthreads();
    for (int d = 1; d < 256; d <<= 1) {
        int add = (t >= d) ? s[t - d] : 0;
        __syncthreads();
        s[t] += add;
        __syncthreads();
    }
    int o = s[t] - c;
#pragma unroll
    for (int i = 0; i < 8; ++i) {
        if (v[i] != 0.f) {
            if (o < ELLW) {
                cols[n * ELLW + o] = t * 8 + i;
                vals[n * ELLW + o] = v[i];
            }
            ++o;
        }
    }
    if (t == 255) cnt[n] = (s[255] < ELLW) ? s[255] : ELLW;
}

// ---------------------------------------------------------------------------
// W [198][256] fp32 -> W_t hi/lo [256][224] bf16 (transposed, K-padded).
// ---------------------------------------------------------------------------
__global__ __launch_bounds__(256) void wt_prep(
    const float* __restrict__ W, short* __restrict__ Wh, short* __restrict__ Wl)
{
    const int col = blockIdx.x;
    const int k = threadIdx.x;
    if (k < KP) {
        const float x = (k < 198) ? W[(size_t)k * GG + col] : 0.f;
        const unsigned short h = f2bf(x);
        const unsigned short l = f2bf(x - bf2f(h));
        Wh[(size_t)col * KP + k] = (short)h;
        Wl[(size_t)col * KP + k] = (short)l;
    }
}

// ---------------------------------------------------------------------------
// t1 = L @ comb. One wave per (b,n) row; lane = feature; unroll-2 for ILP.
// ---------------------------------------------------------------------------
__global__ __launch_bounds__(256) void spmm_t1(
    const float* __restrict__ xin, int xbstride,
    const float* __restrict__ h,
    const int* __restrict__ cols, const float* __restrict__ vals,
    const int* __restrict__ cnt, float* __restrict__ t1)
{
    const int wid = threadIdx.x >> 6, lane = threadIdx.x & 63;
    const int r = blockIdx.x * 4 + wid;
    const int b = r >> 11, n = r & (NN - 1);
    const float* xb = xin + (size_t)b * xbstride;
    const float* hb = h + ((size_t)b << 11) * HH;
    const int* colp = cols + n * ELLW;
    const float* valp = vals + n * ELLW;
    const int cn = cnt[n];
    float a0 = 0.f, a1 = 0.f;
    int j = 0;
    for (; j + 2 <= cn; j += 2) {
        const int m0 = colp[j], m1 = colp[j + 1];
        const float v0 = valp[j], v1 = valp[j + 1];
        const float g0 = (lane < 2) ? xb[m0 * 2 + lane] : hb[(size_t)m0 * HH + lane - 2];
        const float g1 = (lane < 2) ? xb[m1 * 2 + lane] : hb[(size_t)m1 * HH + lane - 2];
        a0 += v0 * g0;
        a0 += v1 * g1;
        if (lane < 2) {
            a1 += v0 * hb[(size_t)m0 * HH + 62 + lane];
            a1 += v1 * hb[(size_t)m1 * HH + 62 + lane];
        }
    }
    if (j < cn) {
        const int m0 = colp[j];
        const float v0 = valp[j];
        const float g0 = (lane < 2) ? xb[m0 * 2 + lane] : hb[(size_t)m0 * HH + lane - 2];
        a0 += v0 * g0;
        if (lane < 2) a1 += v0 * hb[(size_t)m0 * HH + 62 + lane];
    }
    float* o = t1 + (size_t)r * 66;
    o[lane] = a0;
    if (lane < 2) o[64 + lane] = a1;
}

// ---------------------------------------------------------------------------
// t2 = 2 * (L @ t1) - comb. Same structure as spmm_t1, gathering t1 rows.
// ---------------------------------------------------------------------------
__global__ __launch_bounds__(256) void spmm_t2(
    const float* __restrict__ xin, int xbstride,
    const float* __restrict__ h,
    const int* __restrict__ cols, const float* __restrict__ vals,
    const int* __restrict__ cnt, const float* __restrict__ t1,
    float* __restrict__ t2)
{
    const int wid = threadIdx.x >> 6, lane = threadIdx.x & 63;
    const int r = blockIdx.x * 4 + wid;
    const int b = r >> 11, n = r & (NN - 1);
    const float* xb = xin + (size_t)b * xbstride;
    const float* hb = h + ((size_t)b << 11) * HH;
    const float* t1b = t1 + (((size_t)b << 11)) * 66;
    const int* colp = cols + n * ELLW;
    const float* valp = vals + n * ELLW;
    const int cn = cnt[n];
    float a0 = 0.f, a1 = 0.f;
    int j = 0;
    for (; j + 2 <= cn; j += 2) {
        const int m0 = colp[j], m1 = colp[j + 1];
        const float v0 = valp[j], v1 = valp[j + 1];
        const float g0 = t1b[(size_t)m0 * 66 + lane];
        const float g1 = t1b[(size_t)m1 * 66 + lane];
        a0 += v0 * g0;
        a0 += v1 * g1;
        if (lane < 2) {
            a1 += v0 * t1b[(size_t)m0 * 66 + 64 + lane];
            a1 += v1 * t1b[(size_t)m1 * 66 + 64 + lane];
        }
    }
    if (j < cn) {
        const int m0 = colp[j];
        const float v0 = valp[j];
        a0 += v0 * t1b[(size_t)m0 * 66 + lane];
        if (lane < 2) a1 += v0 * t1b[(size_t)m0 * 66 + 64 + lane];
    }
    const float comb0 = (lane < 2) ? xb[n * 2 + lane] : hb[(size_t)n * HH + lane - 2];
    const float comb1 = (lane < 2) ? hb[(size_t)n * HH + 62 + lane] : 0.f;
    float* o = t2 + (size_t)r * 66;
    o[lane] = 2.f * a0 - comb0;
    if (lane < 2) o[64 + lane] = 2.f * a1 - comb1;
}

// ---------------------------------------------------------------------------
// Fused cell step, split-bf16 MFMA GEMM.
// Block: 256 thr / 4 waves, 64 rows. Wave w owns row-tile rows [16w,16w+16).
// A-tile [64][200] fp32 in LDS (cols 198/199 zero). GEMM vs W_t hi/lo
// (256x224 bf16, [col][k]); acc[ct] f32x4 per 16-col tile.
// C/D layout: col = lane&15, row = (lane>>4)*4 + reg  -> gates lane-local.
// ---------------------------------------------------------------------------
__global__ __launch_bounds__(256) void cell_step(
    const float* __restrict__ xin, int xbstride,
    float* __restrict__ h, float* __restrict__ c,
    const float* __restrict__ t1g, const float* __restrict__ t2g,
    const short* __restrict__ Wh, const short* __restrict__ Wl,
    const float* __restrict__ bc,
    const float* __restrict__ W0, const float* __restrict__ b0,
    float* __restrict__ xout, float* __restrict__ out, int jslot)
{
    __shared__ float A[64][200];
    const int tid = threadIdx.x, wid = tid >> 6, lane = tid & 63;
    const int q = lane >> 4, c16 = lane & 15;
    const int row0 = blockIdx.x * 64;

    // ---- phase 1: stage cheb features (coalesced; t2 precomputed)
    for (int rr = wid; rr < 64; rr += 4) {
        const int r = row0 + rr, b = r >> 11, n = r & (NN - 1);
        const float* xb = xin + (size_t)b * xbstride;
        const float* hb = h + ((size_t)b << 11) * HH;
        A[rr][lane] = (lane < 2) ? xb[n * 2 + lane] : hb[(size_t)n * HH + lane - 2];
        if (lane < 2) A[rr][64 + lane] = hb[(size_t)n * HH + 62 + lane];
        const float* t1r = t1g + (size_t)r * 66;
        A[rr][66 + lane] = t1r[lane];
        if (lane < 2) A[rr][130 + lane] = t1r[64 + lane];
        const float* t2r = t2g + (size_t)r * 66;
        A[rr][132 + lane] = t2r[lane];
        if (lane < 2) A[rr][196 + lane] = t2r[64 + lane];
        if (lane < 2) A[rr][198 + lane] = 0.f;
    }
    __syncthreads();

    // ---- phase 2: MFMA GEMM
    f32x4 acc[16];
#pragma unroll
    for (int ct = 0; ct < 16; ++ct) acc[ct] = (f32x4){0.f, 0.f, 0.f, 0.f};

    const int rowA = wid * 16 + c16;
#pragma unroll 1
    for (int kc = 0; kc < 7; ++kc) {
        const int kb = kc * 32 + q * 8;
        bf16x8 ahi, alo;
        if (kb <= 192) {
            const float4 p0 = *(const float4*)&A[rowA][kb];
            const float4 p1 = *(const float4*)&A[rowA][kb + 4];
            const float av[8] = {p0.x, p0.y, p0.z, p0.w, p1.x, p1.y, p1.z, p1.w};
#pragma unroll
            for (int i = 0; i < 8; ++i) {
                const unsigned short hv = f2bf(av[i]);
                ahi[i] = (short)hv;
                alo[i] = (short)f2bf(av[i] - bf2f(hv));
            }
        } else {
#pragma unroll
            for (int i = 0; i < 8; ++i) { ahi[i] = 0; alo[i] = 0; }
        }
        const int wofs0 = c16 * KP + kc * 32 + q * 8;
#pragma unroll
        for (int ct = 0; ct < 16; ++ct) {
            const int wofs = wofs0 + ct * 16 * KP;
            const bf16x8 bh = *(const bf16x8*)(Wh + wofs);
            const bf16x8 bl = *(const bf16x8*)(Wl + wofs);
            acc[ct] = __builtin_amdgcn_mfma_f32_16x16x32_bf16(ahi, bh, acc[ct], 0, 0, 0);
            acc[ct] = __builtin_amdgcn_mfma_f32_16x16x32_bf16(alo, bh, acc[ct], 0, 0, 0);
            acc[ct] = __builtin_amdgcn_mfma_f32_16x16x32_bf16(ahi, bl, acc[ct], 0, 0, 0);
        }
    }

    // ---- phase 3: LSTM elementwise (lane-local gates) + optional projection
    float h2v[4][4];
#pragma unroll
    for (int tp = 0; tp < 4; ++tp) {
        const int u = 16 * tp + c16;
        const float bi = bc[u], bfv = bc[64 + u], bo = bc[128 + u], bg = bc[192 + u];
#pragma unroll
        for (int reg = 0; reg < 4; ++reg) {
            const int r = row0 + wid * 16 + q * 4 + reg;
            const size_t idx = (size_t)r * HH + u;
            const float ig = sigmoidf_(acc[tp][reg] + bi);
            const float fg = sigmoidf_(acc[4 + tp][reg] + bfv);
            const float og = sigmoidf_(acc[8 + tp][reg] + bo);
            const float gg = tanhf_(acc[12 + tp][reg] + bg);
            const float c2 = fg * c[idx] + ig * gg;
            const float h2 = og * tanhf_(c2);
            c[idx] = c2;
            h[idx] = h2;
            h2v[tp][reg] = h2;
        }
    }

    if (jslot >= 0) {
        const float b00 = b0[0], b01 = b0[1];
        float w0v[4], w1v[4];
#pragma unroll
        for (int tp = 0; tp < 4; ++tp) {
            w0v[tp] = W0[(16 * tp + c16) * 2];
            w1v[tp] = W0[(16 * tp + c16) * 2 + 1];
        }
#pragma unroll
        for (int reg = 0; reg < 4; ++reg) {
            float s0 = 0.f, s1 = 0.f;
#pragma unroll
            for (int tp = 0; tp < 4; ++tp) {
                s0 += h2v[tp][reg] * w0v[tp];
                s1 += h2v[tp][reg] * w1v[tp];
            }
#pragma unroll
            for (int d = 1; d <= 8; d <<= 1) {
                s0 += __shfl_xor(s0, d, 64);
                s1 += __shfl_xor(s1, d, 64);
            }
            if (c16 == 0) {
                const int r = row0 + wid * 16 + q * 4 + reg;
                const int b = r >> 11, n = r & (NN - 1);
                const float y0 = tanhf_(s0 + b00);
                const float y1 = tanhf_(s1 + b01);
                xout[(size_t)r * 2] = y0;
                xout[(size_t)r * 2 + 1] = y1;
                float* op = out + (((size_t)b * FUT + jslot) * NN + n) * 2;
                op[0] = y0;
                op[1] = y1;
            }
        }
    }
}

// ---------------------------------------------------------------------------
extern "C" void kernel_launch(void* const* d_in, const int* in_sizes, int n_in,
                              void* d_out, int out_size, void* d_ws, size_t ws_size,
                              hipStream_t stream)
{
    const float* input = (const float*)d_in[0];   // [B,T,N,2]
    const float* L     = (const float*)d_in[1];   // [N,N]
    const float* W     = (const float*)d_in[2];   // [198,256]
    const float* bc    = (const float*)d_in[3];   // [256]
    const float* W0    = (const float*)d_in[4];   // [64,2]
    const float* b0    = (const float*)d_in[5];   // [2]

    char* ws = (char*)d_ws;
    size_t off = 0;
    auto carve = [&](size_t bytes) {
        void* p = ws + off;
        off += (bytes + 255) & ~(size_t)255;
        return p;
    };
    int*   cols = (int*)  carve((size_t)NN * ELLW * 4);
    float* vals = (float*)carve((size_t)NN * ELLW * 4);
    int*   cnt  = (int*)  carve((size_t)NN * 4);
    float* t1   = (float*)carve((size_t)BB * NN * 66 * 4);
    float* t2   = (float*)carve((size_t)BB * NN * 66 * 4);
    float* h    = (float*)carve((size_t)BB * NN * HH * 4);
    float* c    = (float*)carve((size_t)BB * NN * HH * 4);
    float* xbuf = (float*)carve((size_t)BB * NN * 2 * 4);
    short* Wh   = (short*)carve((size_t)GG * KP * 2);
    short* Wl   = (short*)carve((size_t)GG * KP * 2);
    float* out  = (float*)d_out;

    build_ell<<<NN, 256, 0, stream>>>(L, cols, vals, cnt);
    wt_prep<<<GG, 256, 0, stream>>>(W, Wh, Wl);
    hipMemsetAsync(h, 0, (size_t)BB * NN * HH * 4, stream);
    hipMemsetAsync(c, 0, (size_t)BB * NN * HH * 4, stream);

    const int gridS = (BB * NN) / 4;
    const int gridC = (BB * NN) / 64;

    for (int t = 0; t < TT; ++t) {
        const float* xin = input + (size_t)t * NN * 2;
        const int xstride = TT * NN * 2;
        spmm_t1<<<gridS, 256, 0, stream>>>(xin, xstride, h, cols, vals, cnt, t1);
        spmm_t2<<<gridS, 256, 0, stream>>>(xin, xstride, h, cols, vals, cnt, t1, t2);
        cell_step<<<gridC, 256, 0, stream>>>(xin, xstride, h, c, t1, t2, Wh, Wl,
                                             bc, W0, b0, xbuf, out,
                                             (t == TT - 1) ? 0 : -1);
    }
    for (int j = 1; j < FUT; ++j) {
        spmm_t1<<<gridS, 256, 0, stream>>>(xbuf, NN * 2, h, cols, vals, cnt, t1);
        spmm_t2<<<gridS, 256, 0, stream>>>(xbuf, NN * 2, h, cols, vals, cnt, t1, t2);
        cell_step<<<gridC, 256, 0, stream>>>(xbuf, NN * 2, h, c, t1, t2, Wh, Wl,
                                             bc, W0, b0, xbuf, out, j);
    }
}